// Round 1
// baseline (204.978 us; speedup 1.0000x reference)
//
#include <hip/hip_runtime.h>
#include <hip/hip_bf16.h>

typedef __bf16 bf16_t;
typedef __bf16 bf16x8 __attribute__((ext_vector_type(8)));
typedef __bf16 bf16x4 __attribute__((ext_vector_type(4)));
typedef float  f32x4  __attribute__((ext_vector_type(4)));

#define D_DIM 1024
#define N_LAB 64
#define ST_TOK 16384
#define QT_TOK 16384

// ---------------- Kernel 1: proto scatter-accumulate --------------------
// grid = 256 blocks: blockIdx = dchunk (16, 64 dims each) + 16*tchunk (16, 1024 tokens each)
// LDS accum [64 labels][68 floats] (stride 68 -> bank = (tag*4+dim)%32, spreads tags)
__global__ __launch_bounds__(256) void k_proto_acc(
    const float* __restrict__ s_emb, const int* __restrict__ tag,
    const int* __restrict__ msk, float* __restrict__ protoSum,
    int* __restrict__ counts)
{
    __shared__ float lp[N_LAB][68];
    __shared__ int   lc[N_LAB];
    const int tid    = threadIdx.x;
    const int dchunk = blockIdx.x & 15;
    const int tchunk = blockIdx.x >> 4;

    for (int i = tid; i < N_LAB * 68; i += 256) ((float*)lp)[i] = 0.f;
    if (tid < N_LAB) lc[tid] = 0;
    __syncthreads();

    const int dbase  = dchunk * 64;
    const int t0     = tchunk * 1024;
    const int lane16 = tid & 15;   // covers 16 dims * 4 floats
    const int tsub   = tid >> 4;   // 16 tokens per sweep

    for (int it = 0; it < 64; ++it) {
        const int tok = t0 + it * 16 + tsub;
        const int m = msk[tok];
        if (m) {
            const int tg = tag[tok];
            f32x4 v = *(const f32x4*)(s_emb + (size_t)tok * D_DIM + dbase + lane16 * 4);
            atomicAdd(&lp[tg][lane16 * 4 + 0], v[0]);
            atomicAdd(&lp[tg][lane16 * 4 + 1], v[1]);
            atomicAdd(&lp[tg][lane16 * 4 + 2], v[2]);
            atomicAdd(&lp[tg][lane16 * 4 + 3], v[3]);
            if (dchunk == 0 && lane16 == 0) atomicAdd(&lc[tg], 1);
        }
    }
    __syncthreads();

    for (int i = tid; i < N_LAB * 64; i += 256) {
        const int n = i >> 6, d = i & 63;
        atomicAdd(&protoSum[n * D_DIM + dbase + d], lp[n][d]);
    }
    if (dchunk == 0 && tid < N_LAB) atomicAdd(&counts[tid], lc[tid]);
}

// ---------------- Kernel 2: finalize protos -----------------------------
// 64 blocks (one label each) x 256 threads; thread handles 4 dims.
__global__ __launch_bounds__(256) void k_finalize(
    const float* __restrict__ protoSum, const int* __restrict__ counts,
    bf16_t* __restrict__ protoB, float* __restrict__ p2)
{
    const int n = blockIdx.x;
    const int tid = threadIdx.x;
    const float inv = 1.f / fmaxf((float)counts[n], 1.f);

    f32x4 v = *(const f32x4*)(protoSum + n * D_DIM + tid * 4);
    float a0 = v[0] * inv, a1 = v[1] * inv, a2 = v[2] * inv, a3 = v[3] * inv;
    float ss = a0 * a0 + a1 * a1 + a2 * a2 + a3 * a3;

    bf16x4 b;
    b[0] = (bf16_t)a0; b[1] = (bf16_t)a1; b[2] = (bf16_t)a2; b[3] = (bf16_t)a3;
    *(bf16x4*)(protoB + n * D_DIM + tid * 4) = b;

    // block reduction of ss
    for (int off = 32; off; off >>= 1) ss += __shfl_down(ss, off);
    __shared__ float red[4];
    if ((tid & 63) == 0) red[tid >> 6] = ss;
    __syncthreads();
    if (tid == 0) p2[n] = red[0] + red[1] + red[2] + red[3];
}

// ---------------- Kernel 3: logits via bf16 MFMA ------------------------
// 256 blocks x 256 threads (4 waves). Wave: 16 query rows x all 64 labels.
// A frag: A[m=lane&15][k=quad*8+j]; B frag: B[k][n=lane&15], k=quad*8+j
// (B[k][n] = proto[n][k]). C/D: col=lane&15, row=quad*4+reg.
__global__ __launch_bounds__(256) void k_logits(
    const float* __restrict__ q_emb, const int* __restrict__ q_mask,
    const bf16_t* __restrict__ protoB, const float* __restrict__ p2,
    float* __restrict__ out)
{
    const int tid  = threadIdx.x;
    const int wave = tid >> 6;
    const int lane = tid & 63;
    const int r15  = lane & 15;
    const int quad = lane >> 4;
    const int m_base = blockIdx.x * 64 + wave * 16;

    const float*  aptr = q_emb  + (size_t)(m_base + r15) * D_DIM + quad * 8;
    const bf16_t* bptr = protoB + (size_t)r15 * D_DIM + quad * 8;

    f32x4 acc[4] = {};
    float q2p = 0.f;

    for (int kk = 0; kk < D_DIM; kk += 32) {
        f32x4 a0 = *(const f32x4*)(aptr + kk);
        f32x4 a1 = *(const f32x4*)(aptr + kk + 4);
        bf16x8 af;
        af[0] = (bf16_t)a0[0]; af[1] = (bf16_t)a0[1];
        af[2] = (bf16_t)a0[2]; af[3] = (bf16_t)a0[3];
        af[4] = (bf16_t)a1[0]; af[5] = (bf16_t)a1[1];
        af[6] = (bf16_t)a1[2]; af[7] = (bf16_t)a1[3];
        q2p += a0[0]*a0[0] + a0[1]*a0[1] + a0[2]*a0[2] + a0[3]*a0[3]
             + a1[0]*a1[0] + a1[1]*a1[1] + a1[2]*a1[2] + a1[3]*a1[3];
#pragma unroll
        for (int t = 0; t < 4; ++t) {
            bf16x8 bfr = *(const bf16x8*)(bptr + (size_t)t * 16 * D_DIM + kk);
            acc[t] = __builtin_amdgcn_mfma_f32_16x16x32_bf16(af, bfr, acc[t], 0, 0, 0);
        }
    }

    // q2p currently: partial sum for row r15 over this quad's k-subset.
    // Reduce across the 4 quads holding the same r15.
    q2p += __shfl_xor(q2p, 16);
    q2p += __shfl_xor(q2p, 32);
    // now lane l holds full q2 of row (l & 15)

    float p2v[4];
#pragma unroll
    for (int t = 0; t < 4; ++t) p2v[t] = p2[t * 16 + r15];

#pragma unroll
    for (int r = 0; r < 4; ++r) {
        const int mrow = quad * 4 + r;
        const float q2 = __shfl(q2p, mrow);     // lane mrow holds q2[row=mrow]
        const int gm = m_base + mrow;
        const float qm = (float)q_mask[gm];
#pragma unroll
        for (int t = 0; t < 4; ++t) {
            const float val = -(q2 + p2v[t] - 2.f * acc[t][r]) * qm;
            out[(size_t)gm * N_LAB + t * 16 + r15] = val;
        }
    }
}

extern "C" void kernel_launch(void* const* d_in, const int* in_sizes, int n_in,
                              void* d_out, int out_size, void* d_ws, size_t ws_size,
                              hipStream_t stream) {
    const float* s_emb = (const float*)d_in[0];
    const int*   s_tag = (const int*)d_in[1];
    const int*   s_msk = (const int*)d_in[2];
    const float* q_emb = (const float*)d_in[3];
    const int*   q_msk = (const int*)d_in[4];
    (void)in_sizes; (void)n_in; (void)out_size; (void)ws_size;

    char* ws = (char*)d_ws;
    float*  protoSum = (float*)ws;                   // 64*1024*4   = 262144 B
    int*    counts   = (int*)(ws + 262144);          // 64*4        = 256 B
    bf16_t* protoB   = (bf16_t*)(ws + 262400);       // 64*1024*2   = 131072 B (16B-aligned)
    float*  p2       = (float*)(ws + 393472);        // 64*4        = 256 B

    hipMemsetAsync(ws, 0, 262400, stream);
    hipLaunchKernelGGL(k_proto_acc, dim3(256), dim3(256), 0, stream,
                       s_emb, s_tag, s_msk, protoSum, counts);
    hipLaunchKernelGGL(k_finalize, dim3(64), dim3(256), 0, stream,
                       protoSum, counts, protoB, p2);
    hipLaunchKernelGGL(k_logits, dim3(256), dim3(256), 0, stream,
                       q_emb, q_msk, protoB, p2, (float*)d_out);
}